// Round 10
// baseline (204.776 us; speedup 1.0000x reference)
//
#include <hip/hip_runtime.h>
#include <hip/hip_bf16.h>

#define N_NODES 20000
#define N_EDGES 640000
#define NRELS 20
#define MAXB 16            // bucket capacity per (node,rel); Poisson(1.6) -> safe

typedef __attribute__((ext_vector_type(8))) short short8;
typedef __attribute__((ext_vector_type(8))) unsigned short ushort8;
typedef __attribute__((ext_vector_type(4))) float floatx4;
typedef unsigned short u16;
typedef unsigned int u32;

__device__ __forceinline__ float bf2f(u16 u){
  union { u32 i; float f; } v; v.i = ((u32)u) << 16; return v.f;
}
__device__ __forceinline__ u16 f2bf(float f){
  __hip_bfloat16 b = __float2bfloat16(f);
  return __builtin_bit_cast(u16, b);
}

// ---- K0: fused {cast h->bf16 + (dst,rel)-bucket fill} | {wfrag} -------------
// wfrag layout: [rel][frag = ks*8+nf][lane][8 bf16]  (MFMA fragment order)
__global__ __launch_bounds__(256) void k_prep(
    const float* __restrict__ h, u16* __restrict__ hb,
    const int* __restrict__ src, const int* __restrict__ dst,
    const int* __restrict__ ety, int* __restrict__ counts2, int* __restrict__ gidx2,
    const float* __restrict__ weight, const float* __restrict__ w_comp,
    u16* __restrict__ wfrag){
  const int b = blockIdx.x;
  if (b < 2500){
    int tidg = b * 256 + threadIdx.x;            // 640,000 threads: 1 edge + 4 floats
    int i = tidg * 4;
    float4 v = *(const float4*)(h + i);
    u16 o[4] = { f2bf(v.x), f2bf(v.y), f2bf(v.z), f2bf(v.w) };
    *(ushort4*)(hb + i) = *(ushort4*)o;
    int key = dst[tidg] * NRELS + ety[tidg];
    int old = atomicAdd(&counts2[key], 1);
    if (old < MAXB) gidx2[key * MAXB + old] = src[tidg];
  } else {
    int f = (b - 2500) * 256 + threadIdx.x;      // < 20*128*128 exactly
    int i  = f & 127;
    int o  = (f >> 7) & 127;
    int r  = f >> 14;
    int q  = r * 128 + i;                        // reference reshape semantics
    int rr = q % 20, ii = q / 20;
    float acc = 0.f;
    #pragma unroll
    for (int bb = 0; bb < 8; ++bb)
      acc += w_comp[rr * 8 + bb] * weight[ii * 1024 + bb * 128 + o];
    int ks = i >> 5, sub = (i >> 3) & 3, j = i & 7, nf = o >> 4;
    int l  = (sub << 4) | (o & 15);
    wfrag[((r * 32 + ks * 8 + nf) * 64 + l) * 8 + j] = f2bf(acc);
  }
}

// ---- K1: hagg[rel][node] = sum of h_b[src] over bucket (f32 acc, bf16 out) --
// 16 lanes per row, int4 chunks; gathers hit L2-resident hb (5 MB).
__global__ __launch_bounds__(256) void k_hagg(
    const int* __restrict__ counts2, const int* __restrict__ gidx2,
    const u16* __restrict__ hb, u16* __restrict__ hagg){
  const int rid = blockIdx.x * 16 + (threadIdx.x >> 4);  // rel*20000+node
  const int q   = threadIdx.x & 15;
  const int node = rid % N_NODES;
  const int rel  = rid / N_NODES;
  const int key  = node * NRELS + rel;
  int c = counts2[key]; c = (c > MAXB) ? MAXB : c;
  const int* gb = gidx2 + key * MAXB;
  float acc[8] = {0.f,0.f,0.f,0.f,0.f,0.f,0.f,0.f};
  for (int j = 0; j < c; ++j){
    int s = gb[j];                               // broadcast within 16-lane group
    int4 v = *(const int4*)(hb + (size_t)s * 128 + q * 8);
    u32 w;
    w = (u32)v.x; acc[0] += bf2f((u16)(w & 0xffffu)); acc[1] += bf2f((u16)(w >> 16));
    w = (u32)v.y; acc[2] += bf2f((u16)(w & 0xffffu)); acc[3] += bf2f((u16)(w >> 16));
    w = (u32)v.z; acc[4] += bf2f((u16)(w & 0xffffu)); acc[5] += bf2f((u16)(w >> 16));
    w = (u32)v.w; acc[6] += bf2f((u16)(w & 0xffffu)); acc[7] += bf2f((u16)(w >> 16));
  }
  ushort8 u;
  #pragma unroll
  for (int k = 0; k < 8; ++k) u[k] = f2bf(acc[k]);
  *(ushort8*)(hagg + (size_t)rid * 128 + q * 8) = u;     // natural i-order
}

// ---- K2: out = relu( sum_r hagg[r] @ W_r )  (K=2560 accumulation) -----------
__global__ __launch_bounds__(256, 4) void k_gemmK(
    const u16* __restrict__ hagg, const u16* __restrict__ wfrag,
    float* __restrict__ out){
  __shared__ u16 Bs[16384];                      // 32 KB fragment-major
  const int m0   = blockIdx.x * 64;
  const int tid  = threadIdx.x;
  const int wave = tid >> 6, lane = tid & 63;
  const int arow = m0 + wave * 16 + (lane & 15);
  const int ak   = (lane >> 4) * 8;
  const bool aok = arow < N_NODES;
  const short8 az = __builtin_bit_cast(short8, make_int4(0, 0, 0, 0));
  const char* lbase = (const char*)Bs + lane * 16;
  floatx4 acc[8] = {};
  for (int rel = 0; rel < NRELS; ++rel){
    // issue A loads first: latency hides under stage + barrier
    short8 a[4];
    #pragma unroll
    for (int ks = 0; ks < 4; ++ks)
      a[ks] = aok ? *(const short8*)(hagg + ((size_t)rel * N_NODES + arow) * 128
                                     + ks * 32 + ak) : az;
    __syncthreads();                             // prior-phase Bs reads done
    {                                            // linear 32KB stage, coalesced
      const u16* wb = wfrag + rel * 16384;
      #pragma unroll
      for (int jj = 0; jj < 8; ++jj){
        int idx = tid + jj * 256;
        *(int4*)((char*)Bs + idx * 16) = *(const int4*)(wb + idx * 8);
      }
    }
    __syncthreads();
    #pragma unroll
    for (int ks = 0; ks < 4; ++ks)
      #pragma unroll
      for (int nf = 0; nf < 8; ++nf){
        short8 bfr = *(const short8*)(lbase + ((ks * 8 + nf) << 10));
        acc[nf] = __builtin_amdgcn_mfma_f32_16x16x32_bf16(a[ks], bfr, acc[nf], 0, 0, 0);
      }
  }
  // epilogue: relu + direct f32 store (16-lane x 64 B contiguous runs)
  #pragma unroll
  for (int nf = 0; nf < 8; ++nf){
    int col = nf * 16 + (lane & 15);
    #pragma unroll
    for (int j = 0; j < 4; ++j){
      int row = m0 + wave * 16 + ((lane >> 4) << 2) + j;   // C/D row=(l>>4)*4+j
      if (row < N_NODES)
        out[(size_t)row * 128 + col] = fmaxf(acc[nf][j], 0.f);
    }
  }
}

// ---- launcher ---------------------------------------------------------------
extern "C" void kernel_launch(void* const* d_in, const int* in_sizes, int n_in,
                              void* d_out, int out_size, void* d_ws, size_t ws_size,
                              hipStream_t stream){
  const float* h      = (const float*)d_in[0];
  const float* weight = (const float*)d_in[1];
  const float* w_comp = (const float*)d_in[2];
  const int* src      = (const int*)d_in[3];
  const int* dst      = (const int*)d_in[4];
  const int* etype    = (const int*)d_in[5];
  float* out = (float*)d_out;

  char* p = (char*)d_ws;
  u16* hagg    = (u16*)p;  p += 102400000;       // [20][20000][128] bf16
  u16* hb      = (u16*)p;  p += 5120000;
  u16* wfrag   = (u16*)p;  p += 655360;
  int* counts2 = (int*)p;  p += 1600000;         // 400,000 (dst,rel) keys
  int* gidx2   = (int*)p;  /* 400,000*16*4 = 25,600,000 B */  // total ~135.4 MB

  hipMemsetAsync(counts2, 0, 400000 * sizeof(int), stream);
  k_prep <<<dim3(3780), dim3(256), 0, stream>>>(h, hb, src, dst, etype,
                                                counts2, gidx2, weight, w_comp, wfrag);
  k_hagg <<<dim3(400000 / 16), dim3(256), 0, stream>>>(counts2, gidx2, hb, hagg);
  k_gemmK<<<dim3(313), dim3(256), 0, stream>>>(hagg, wfrag, out);
}

// Round 11
// 185.769 us; speedup vs baseline: 1.1023x; 1.1023x over previous
//
#include <hip/hip_runtime.h>
#include <hip/hip_bf16.h>

#define N_NODES 20000
#define N_EDGES 640000
#define NRELS 20
#define SHB 32             // bucket capacity per (node,shard): Poisson(8), safe
#define GEMM_V 800         // 8 XCDs * 20 tile-pairs * 5 rel-groups (24 dead)
#define FILL_BLOCKS 2500   // 640000 / 256

typedef __attribute__((ext_vector_type(8))) short short8;
typedef __attribute__((ext_vector_type(8))) unsigned short ushort8;
typedef __attribute__((ext_vector_type(4))) float floatx4;
typedef unsigned short u16;
typedef unsigned int u32;

__device__ __forceinline__ float bf2f(u16 u){
  union { u32 i; float f; } v; v.i = ((u32)u) << 16; return v.f;
}
__device__ __forceinline__ u16 f2bf(float f){
  __hip_bfloat16 b = __float2bfloat16(f);
  return __builtin_bit_cast(u16, b);
}

// ---- K0: fused {cast h->bf16 + 4-shard count/rank} | {wfrag} ----------------
// wfrag layout: [rel][frag = ks*8+nf][lane][8 bf16]  (MFMA fragment order)
__global__ __launch_bounds__(256) void k_prep(
    const float* __restrict__ h, u16* __restrict__ hb,
    const int* __restrict__ dst, int* __restrict__ counts4, int* __restrict__ rank,
    const float* __restrict__ weight, const float* __restrict__ w_comp,
    u16* __restrict__ wfrag){
  const int b = blockIdx.x;
  if (b < 2500){
    int tidg = b * 256 + threadIdx.x;
    int i = tidg * 4;
    float4 v = *(const float4*)(h + i);
    u16 o[4] = { f2bf(v.x), f2bf(v.y), f2bf(v.z), f2bf(v.w) };
    *(ushort4*)(hb + i) = *(ushort4*)o;
    rank[tidg] = atomicAdd(&counts4[(b & 3) * N_NODES + dst[tidg]], 1);
  } else {
    int f = (b - 2500) * 256 + threadIdx.x;      // < 20*128*128 exactly
    int i  = f & 127;
    int o  = (f >> 7) & 127;
    int r  = f >> 14;
    int q  = r * 128 + i;                        // reference reshape semantics
    int rr = q % 20, ii = q / 20;
    float acc = 0.f;
    #pragma unroll
    for (int bb = 0; bb < 8; ++bb)
      acc += w_comp[rr * 8 + bb] * weight[ii * 1024 + bb * 128 + o];
    int ks = i >> 5, sub = (i >> 3) & 3, j = i & 7, nf = o >> 4;
    int l  = (sub << 4) | (o & 15);
    wfrag[((r * 32 + ks * 8 + nf) * 64 + l) * 8 + j] = f2bf(acc);
  }
}

// ---- K1: GEMM (2x64-row tiles x 4 rels, A-regs, frag-major B) + bucket fill -
// xW rows PERMUTED: position p = (c&15)*8 + (c>>4); stores are ushort8.
__global__ __launch_bounds__(256, 4) void k_gemm_fill(
    const u16* __restrict__ hb, const u16* __restrict__ wfrag, u16* __restrict__ xW,
    const int* __restrict__ dst, const int* __restrict__ srcv,
    const int* __restrict__ ety, const int* __restrict__ rank,
    int* __restrict__ gidx){
  if (blockIdx.x >= GEMM_V){                     // ---- fill role (overlapped) -
    int e = (blockIdx.x - GEMM_V) * 256 + threadIdx.x;
    if (e < N_EDGES){
      int sh = (e >> 8) & 3;                     // matches prep's (b&3)
      int rk = rank[e];
      if (rk < SHB)
        gidx[dst[e] * 128 + sh * SHB + rk] = ety[e] * N_NODES + srcv[e];
    }
    return;
  }
  // ---- gemm role: XCD-co-located 128-row tile-pair x 4 relations ----
  const int vb = blockIdx.x;
  const int x  = vb & 7;                         // XCD (bid % 8 round-robin)
  const int k  = vb >> 3;                        // 0..99
  const int tp = x * 20 + k / 5;                 // tile-pair 0..159
  const int rg = k % 5;
  if (tp >= 157) return;
  __shared__ u16 Bs[16384];                      // 32 KB fragment-major
  const int m0   = tp * 128;
  const int tid  = threadIdx.x;
  const int wave = tid >> 6, lane = tid & 63;
  const int lrow = lane & 15;
  const int ak   = (lane >> 4) * 8;
  const short8 az = __builtin_bit_cast(short8, make_int4(0, 0, 0, 0));
  // A fragments for both 64-row tiles, in registers
  short8 a0[4], a1[4];
  const int ar0 = m0 + wave * 16 + lrow;
  const int ar1 = ar0 + 64;
  const bool ok0 = ar0 < N_NODES, ok1 = ar1 < N_NODES;
  #pragma unroll
  for (int ks = 0; ks < 4; ++ks){
    a0[ks] = ok0 ? *(const short8*)(hb + (size_t)ar0 * 128 + ks * 32 + ak) : az;
    a1[ks] = ok1 ? *(const short8*)(hb + (size_t)ar1 * 128 + ks * 32 + ak) : az;
  }
  const char* lbase = (const char*)Bs + lane * 16;
  for (int rb = 0; rb < 4; ++rb){
    const int rel = rg * 4 + rb;
    __syncthreads();                             // prior-phase Bs reads done
    {                                            // linear 32KB stage, coalesced
      const u16* wb = wfrag + rel * 16384;
      #pragma unroll
      for (int jj = 0; jj < 8; ++jj){
        int idx = tid + jj * 256;
        *(int4*)((char*)Bs + idx * 16) = *(const int4*)(wb + idx * 8);
      }
    }
    __syncthreads();
    floatx4 acc0[8] = {}, acc1[8] = {};
    #pragma unroll
    for (int ks = 0; ks < 4; ++ks)
      #pragma unroll
      for (int nf = 0; nf < 8; ++nf){
        short8 bfr = *(const short8*)(lbase + ((ks * 8 + nf) << 10));
        acc0[nf] = __builtin_amdgcn_mfma_f32_16x16x32_bf16(a0[ks], bfr, acc0[nf], 0, 0, 0);
        acc1[nf] = __builtin_amdgcn_mfma_f32_16x16x32_bf16(a1[ks], bfr, acc1[nf], 0, 0, 0);
      }
    const size_t rbase = (size_t)rel * N_NODES;
    #pragma unroll
    for (int j = 0; j < 4; ++j){
      int row0 = m0 + wave * 16 + ((lane >> 4) << 2) + j;  // C/D row=(l>>4)*4+j
      if (row0 < N_NODES){
        ushort8 u;
        #pragma unroll
        for (int nf = 0; nf < 8; ++nf) u[nf] = f2bf(acc0[nf][j]);
        *(ushort8*)(xW + (rbase + row0) * 128 + lrow * 8) = u;
      }
      int row1 = row0 + 64;
      if (row1 < N_NODES){
        ushort8 u;
        #pragma unroll
        for (int nf = 0; nf < 8; ++nf) u[nf] = f2bf(acc1[nf][j]);
        *(ushort8*)(xW + (rbase + row1) * 128 + lrow * 8) = u;
      }
    }
  }
}

// ---- K2: gather + segment-sum + relu (4 shard-runs, int4, 16 lanes/node) ----
__global__ __launch_bounds__(256) void k_agg(const int* __restrict__ counts4,
    const int* __restrict__ gidx, const u16* __restrict__ xW, float* __restrict__ out){
  const int n = blockIdx.x * 16 + (threadIdx.x >> 4);   // 16 nodes/block
  const int q = threadIdx.x & 15;                        // 16B chunk owner
  float acc[2][8];
  #pragma unroll
  for (int bk = 0; bk < 2; ++bk)
    #pragma unroll
    for (int m = 0; m < 8; ++m) acc[bk][m] = 0.f;
  #pragma unroll
  for (int sh = 0; sh < 4; ++sh){
    int len = counts4[sh * N_NODES + n];
    len = (len > SHB) ? SHB : len;
    const int* gb = gidx + n * 128 + sh * SHB;
    int e = 0;
    for (; e + 8 <= len; e += 8){
      int g[8];
      #pragma unroll
      for (int j = 0; j < 8; ++j) g[j] = gb[e + j];
      #pragma unroll
      for (int j = 0; j < 8; ++j){
        int4 v = *(const int4*)(xW + (size_t)g[j] * 128 + q * 8);
        float* A = acc[j & 1];
        u32 w;
        w = (u32)v.x; A[0] += bf2f((u16)(w & 0xffffu)); A[1] += bf2f((u16)(w >> 16));
        w = (u32)v.y; A[2] += bf2f((u16)(w & 0xffffu)); A[3] += bf2f((u16)(w >> 16));
        w = (u32)v.z; A[4] += bf2f((u16)(w & 0xffffu)); A[5] += bf2f((u16)(w >> 16));
        w = (u32)v.w; A[6] += bf2f((u16)(w & 0xffffu)); A[7] += bf2f((u16)(w >> 16));
      }
    }
    for (; e < len; ++e){
      int4 v = *(const int4*)(xW + (size_t)gb[e] * 128 + q * 8);
      float* A = acc[0];
      u32 w;
      w = (u32)v.x; A[0] += bf2f((u16)(w & 0xffffu)); A[1] += bf2f((u16)(w >> 16));
      w = (u32)v.y; A[2] += bf2f((u16)(w & 0xffffu)); A[3] += bf2f((u16)(w >> 16));
      w = (u32)v.z; A[4] += bf2f((u16)(w & 0xffffu)); A[5] += bf2f((u16)(w >> 16));
      w = (u32)v.w; A[6] += bf2f((u16)(w & 0xffffu)); A[7] += bf2f((u16)(w >> 16));
    }
  }
  // position p = q*8+m -> channel c = m*16 + q
  #pragma unroll
  for (int m = 0; m < 8; ++m)
    out[(size_t)n * 128 + m * 16 + q] = fmaxf(acc[0][m] + acc[1][m], 0.f);
}

// ---- launcher ---------------------------------------------------------------
extern "C" void kernel_launch(void* const* d_in, const int* in_sizes, int n_in,
                              void* d_out, int out_size, void* d_ws, size_t ws_size,
                              hipStream_t stream){
  const float* h      = (const float*)d_in[0];
  const float* weight = (const float*)d_in[1];
  const float* w_comp = (const float*)d_in[2];
  const int* src      = (const int*)d_in[3];
  const int* dst      = (const int*)d_in[4];
  const int* etype    = (const int*)d_in[5];
  float* out = (float*)d_out;

  char* p = (char*)d_ws;
  u16* xW      = (u16*)p;  p += 102400000;       // [20][20000][128] bf16 (perm rows)
  u16* hb      = (u16*)p;  p += 5120000;
  u16* wfrag   = (u16*)p;  p += 655360;
  int* counts4 = (int*)p;  p += 320000;          // 4 shards x 20000
  int* rank    = (int*)p;  p += 2560000;
  int* gidx    = (int*)p;  /* 20000*128*4 = 10,240,000 B */  // total ~121 MB

  hipMemsetAsync(counts4, 0, 4 * N_NODES * sizeof(int), stream);
  k_prep<<<dim3(3780), dim3(256), 0, stream>>>(h, hb, dst, counts4, rank,
                                               weight, w_comp, wfrag);
  k_gemm_fill<<<dim3(GEMM_V + FILL_BLOCKS), dim3(256), 0, stream>>>(
      hb, wfrag, xW, dst, src, etype, rank, gidx);
  k_agg<<<dim3(N_NODES / 16), dim3(256), 0, stream>>>(counts4, gidx, xW, out);
}

// Round 12
// 173.720 us; speedup vs baseline: 1.1788x; 1.0694x over previous
//
#include <hip/hip_runtime.h>
#include <hip/hip_bf16.h>

#define N_NODES 20000
#define N_EDGES 640000
#define NRELS 20
#define MAXDEG 96
#define GEMM_V 800         // 8 XCDs * 20 tile-pairs * 5 rel-groups (24 dead)
#define FILL_BLOCKS 2500   // 640000 / 256

typedef __attribute__((ext_vector_type(8))) short short8;
typedef __attribute__((ext_vector_type(8))) unsigned short ushort8;
typedef __attribute__((ext_vector_type(4))) float floatx4;
typedef unsigned short u16;
typedef unsigned int u32;

__device__ __forceinline__ float bf2f(u16 u){
  union { u32 i; float f; } v; v.i = ((u32)u) << 16; return v.f;
}
__device__ __forceinline__ u16 f2bf(float f){
  __hip_bfloat16 b = __float2bfloat16(f);
  return __builtin_bit_cast(u16, b);
}

// ---- K0: fused {cast h->bf16 + count + rank} | {wfrag} ----------------------
// wfrag layout: [rel][frag = ks*8+nf][lane][8 bf16]  (MFMA fragment order)
__global__ __launch_bounds__(256) void k_prep(
    const float* __restrict__ h, u16* __restrict__ hb,
    const int* __restrict__ dst, int* __restrict__ counts, int* __restrict__ rank,
    const float* __restrict__ weight, const float* __restrict__ w_comp,
    u16* __restrict__ wfrag){
  const int b = blockIdx.x;
  if (b < 2500){
    int tidg = b * 256 + threadIdx.x;
    int i = tidg * 4;
    float4 v = *(const float4*)(h + i);
    u16 o[4] = { f2bf(v.x), f2bf(v.y), f2bf(v.z), f2bf(v.w) };
    *(ushort4*)(hb + i) = *(ushort4*)o;
    rank[tidg] = atomicAdd(&counts[dst[tidg]], 1);
  } else {
    int f = (b - 2500) * 256 + threadIdx.x;      // < 20*128*128 exactly
    int i  = f & 127;
    int o  = (f >> 7) & 127;
    int r  = f >> 14;
    int q  = r * 128 + i;                        // reference reshape semantics
    int rr = q % 20, ii = q / 20;
    float acc = 0.f;
    #pragma unroll
    for (int bb = 0; bb < 8; ++bb)
      acc += w_comp[rr * 8 + bb] * weight[ii * 1024 + bb * 128 + o];
    int ks = i >> 5, sub = (i >> 3) & 3, j = i & 7, nf = o >> 4;
    int l  = (sub << 4) | (o & 15);
    wfrag[((r * 32 + ks * 8 + nf) * 64 + l) * 8 + j] = f2bf(acc);
  }
}

// ---- K1: GEMM (2x64-row tiles x 4 rels, A-regs, frag-major B) + CSR fill ----
// xW rows PERMUTED: position p = (c&15)*8 + (c>>4); stores are ushort8.
__global__ __launch_bounds__(256, 4) void k_gemm_fill(
    const u16* __restrict__ hb, const u16* __restrict__ wfrag, u16* __restrict__ xW,
    const int* __restrict__ dst, const int* __restrict__ srcv,
    const int* __restrict__ ety, const int* __restrict__ rank,
    int* __restrict__ gidx){
  if (blockIdx.x >= GEMM_V){                     // ---- fill role (overlapped) -
    int e = (blockIdx.x - GEMM_V) * 256 + threadIdx.x;
    if (e < N_EDGES)
      gidx[dst[e] * MAXDEG + rank[e]] = ety[e] * N_NODES + srcv[e];
    return;
  }
  // ---- gemm role: XCD-co-located 128-row tile-pair x 4 relations ----
  const int vb = blockIdx.x;
  const int x  = vb & 7;                         // XCD (bid % 8 round-robin)
  const int k  = vb >> 3;                        // 0..99
  const int tp = x * 20 + k / 5;                 // tile-pair 0..159
  const int rg = k % 5;
  if (tp >= 157) return;
  __shared__ u16 Bs[16384];                      // 32 KB fragment-major
  const int m0   = tp * 128;
  const int tid  = threadIdx.x;
  const int wave = tid >> 6, lane = tid & 63;
  const int lrow = lane & 15;
  const int ak   = (lane >> 4) * 8;
  const short8 az = __builtin_bit_cast(short8, make_int4(0, 0, 0, 0));
  short8 a0[4], a1[4];
  const int ar0 = m0 + wave * 16 + lrow;
  const int ar1 = ar0 + 64;
  const bool ok0 = ar0 < N_NODES, ok1 = ar1 < N_NODES;
  #pragma unroll
  for (int ks = 0; ks < 4; ++ks){
    a0[ks] = ok0 ? *(const short8*)(hb + (size_t)ar0 * 128 + ks * 32 + ak) : az;
    a1[ks] = ok1 ? *(const short8*)(hb + (size_t)ar1 * 128 + ks * 32 + ak) : az;
  }
  const char* lbase = (const char*)Bs + lane * 16;
  for (int rb = 0; rb < 4; ++rb){
    const int rel = rg * 4 + rb;
    __syncthreads();                             // prior-phase Bs reads done
    {                                            // linear 32KB stage, coalesced
      const u16* wb = wfrag + rel * 16384;
      #pragma unroll
      for (int jj = 0; jj < 8; ++jj){
        int idx = tid + jj * 256;
        *(int4*)((char*)Bs + idx * 16) = *(const int4*)(wb + idx * 8);
      }
    }
    __syncthreads();
    floatx4 acc0[8] = {}, acc1[8] = {};
    #pragma unroll
    for (int ks = 0; ks < 4; ++ks)
      #pragma unroll
      for (int nf = 0; nf < 8; ++nf){
        short8 bfr = *(const short8*)(lbase + ((ks * 8 + nf) << 10));
        acc0[nf] = __builtin_amdgcn_mfma_f32_16x16x32_bf16(a0[ks], bfr, acc0[nf], 0, 0, 0);
        acc1[nf] = __builtin_amdgcn_mfma_f32_16x16x32_bf16(a1[ks], bfr, acc1[nf], 0, 0, 0);
      }
    const size_t rbase = (size_t)rel * N_NODES;
    #pragma unroll
    for (int j = 0; j < 4; ++j){
      int row0 = m0 + wave * 16 + ((lane >> 4) << 2) + j;  // C/D row=(l>>4)*4+j
      if (row0 < N_NODES){
        ushort8 u;
        #pragma unroll
        for (int nf = 0; nf < 8; ++nf) u[nf] = f2bf(acc0[nf][j]);
        *(ushort8*)(xW + (rbase + row0) * 128 + lrow * 8) = u;
      }
      int row1 = row0 + 64;
      if (row1 < N_NODES){
        ushort8 u;
        #pragma unroll
        for (int nf = 0; nf < 8; ++nf) u[nf] = f2bf(acc1[nf][j]);
        *(ushort8*)(xW + (rbase + row1) * 128 + lrow * 8) = u;
      }
    }
  }
}

// ---- K2: gather + sum + relu (8 lanes/node, mask-FMA, 16 loads in flight) ---
__device__ __forceinline__ void acc8(float m, int4 v, float* A){
  u32 w;
  w = (u32)v.x; A[0] = fmaf(m, bf2f((u16)w), A[0]); A[1] = fmaf(m, bf2f((u16)(w >> 16)), A[1]);
  w = (u32)v.y; A[2] = fmaf(m, bf2f((u16)w), A[2]); A[3] = fmaf(m, bf2f((u16)(w >> 16)), A[3]);
  w = (u32)v.z; A[4] = fmaf(m, bf2f((u16)w), A[4]); A[5] = fmaf(m, bf2f((u16)(w >> 16)), A[5]);
  w = (u32)v.w; A[6] = fmaf(m, bf2f((u16)w), A[6]); A[7] = fmaf(m, bf2f((u16)(w >> 16)), A[7]);
}

__global__ __launch_bounds__(256) void k_agg(const int* __restrict__ counts,
    const int* __restrict__ gidx, const u16* __restrict__ xW, float* __restrict__ out){
  const int n  = blockIdx.x * 32 + (threadIdx.x >> 3);  // 32 nodes/block
  const int q8 = threadIdx.x & 7;                       // owns 32 B = 16 ch
  const int len = counts[n];
  const int* gb = gidx + n * MAXDEG;
  float acc[16];
  #pragma unroll
  for (int k = 0; k < 16; ++k) acc[k] = 0.f;
  for (int e = 0; e < len; e += 8){
    #pragma unroll
    for (int j = 0; j < 8; ++j){
      const bool ok = (e + j) < len;
      const int  g  = ok ? gb[e + j] : 0;        // row 0 always valid
      const float m = ok ? 1.f : 0.f;            // mask-FMA kills remainder path
      const u16* row = xW + (size_t)g * 128 + q8 * 16;
      int4 v0 = *(const int4*)(row);
      int4 v1 = *(const int4*)(row + 8);
      acc8(m, v0, acc);
      acc8(m, v1, acc + 8);
    }
  }
  // position p = q8*16+k -> channel c = (p&7)*16 + (p>>3)
  #pragma unroll
  for (int k = 0; k < 16; ++k){
    int c = (k & 7) * 16 + q8 * 2 + (k >> 3);
    out[(size_t)n * 128 + c] = fmaxf(acc[k], 0.f);
  }
}

// ---- launcher ---------------------------------------------------------------
extern "C" void kernel_launch(void* const* d_in, const int* in_sizes, int n_in,
                              void* d_out, int out_size, void* d_ws, size_t ws_size,
                              hipStream_t stream){
  const float* h      = (const float*)d_in[0];
  const float* weight = (const float*)d_in[1];
  const float* w_comp = (const float*)d_in[2];
  const int* src      = (const int*)d_in[3];
  const int* dst      = (const int*)d_in[4];
  const int* etype    = (const int*)d_in[5];
  float* out = (float*)d_out;

  char* p = (char*)d_ws;
  u16* xW      = (u16*)p;  p += 102400000;       // [20][20000][128] bf16 (perm rows)
  u16* hb      = (u16*)p;  p += 5120000;
  u16* wfrag   = (u16*)p;  p += 655360;
  int* counts  = (int*)p;  p += 80000;
  int* rank    = (int*)p;  p += 2560000;
  int* gidx    = (int*)p;  /* 20000*96*4 = 7,680,000 B */  // total ~118.5 MB

  hipMemsetAsync(counts, 0, N_NODES * sizeof(int), stream);
  k_prep<<<dim3(3780), dim3(256), 0, stream>>>(h, hb, dst, counts, rank,
                                               weight, w_comp, wfrag);
  k_gemm_fill<<<dim3(GEMM_V + FILL_BLOCKS), dim3(256), 0, stream>>>(
      hb, wfrag, xW, dst, src, etype, rank, gidx);
  k_agg<<<dim3(N_NODES / 32), dim3(256), 0, stream>>>(counts, gidx, xW, out);
}